// Round 4
// baseline (419.127 us; speedup 1.0000x reference)
//
#include <hip/hip_runtime.h>
#include <math.h>

// CausalSelfAttention: B=4 T=2048 C=1024 H=16 hd=64.
// I/O dtype: fp32 (per reference contract); internal compute bf16 MFMA.
// Pipeline: Wa^T(f32->bf16) -> QKV GEMM (A=f32 x converted in staging; scatter
// bf16 to [bh][t][64]) -> rope table -> rope apply (Q scaled 1/8) ->
// V transpose -> flash attn -> Wp^T(f32->bf16) -> proj GEMM (out fp32,
// bf16-rounded so low mantissa = 0: disambiguates a bf16-read harness).
//
// ws (u16 elems), peak 33,554,432 u16 = 64 MiB:
//   [0,        8388608)  Qg          ... after attn: WpT over dead Qg
//   [8388608, 16777216)  Kg
//   [16777216,25165824)  Vg          ... after V-transpose: Yb over dead Vg
//   [25165824,28311552)  WaT (bf16)  ... dead after QKV GEMM
//   [28311552,28442624)  rope tab    ... dead after rope_apply
//   [25165824,33554432)  VgT (over dead WaT+tab)

typedef unsigned short u16;
typedef __bf16 bf16x8 __attribute__((ext_vector_type(8)));
typedef float f32x4 __attribute__((ext_vector_type(4)));

#define LOG2E 1.4426950408889634f

__device__ __forceinline__ float b2f(u16 x) {
  union { unsigned u; float f; } c; c.u = ((unsigned)x) << 16; return c.f;
}
__device__ __forceinline__ u16 f2b(float f) {
  union { __bf16 h; u16 u; } c; c.h = (__bf16)f; return c.u;
}

// ---------------- sentinel fill (ws too small signal)
__global__ __launch_bounds__(256) void sentinel_k(u16* __restrict__ out, int n) {
  int i = blockIdx.x * 256 + threadIdx.x;
  if (i < n) out[i] = 0x4480;  // bf16 1024.0
}

// ---------------- transpose fp32 src[R][C] -> bf16 dst[C][R], 64x64 tiles
__global__ __launch_bounds__(256) void transpose_f2b_k(const float* __restrict__ src,
                                                       u16* __restrict__ dst,
                                                       int R, int C) {
  __shared__ u16 tile[64][65];
  int tc = blockIdx.x * 64, tr = blockIdx.y * 64;
  int t = threadIdx.x;
  int rr = t >> 3;
  int c8 = (t & 7) * 8;
#pragma unroll
  for (int i = 0; i < 2; ++i) {
    int r = rr + i * 32;
    f32x4 p0 = *(const f32x4*)(src + (long)(tr + r) * C + tc + c8);
    f32x4 p1 = *(const f32x4*)(src + (long)(tr + r) * C + tc + c8 + 4);
#pragma unroll
    for (int j = 0; j < 4; ++j) {
      tile[r][c8 + j] = f2b(p0[j]);
      tile[r][c8 + 4 + j] = f2b(p1[j]);
    }
  }
  __syncthreads();
#pragma unroll
  for (int i = 0; i < 2; ++i) {
    int a = rr + i * 32;
    u16 vv[8];
#pragma unroll
    for (int j = 0; j < 8; ++j) vv[j] = tile[c8 + j][a];
    *(uint4*)(dst + (long)(tc + a) * R + tr + c8) = *(uint4*)vv;
  }
}

// ---------------- transpose bf16 src[R][C] -> bf16 dst[C][R], batched via z
__global__ __launch_bounds__(256) void transpose_b_k(const u16* __restrict__ src,
                                                     u16* __restrict__ dst,
                                                     int R, int C,
                                                     long sBatch, long dBatch) {
  __shared__ u16 tile[64][65];
  src += (long)blockIdx.z * sBatch;
  dst += (long)blockIdx.z * dBatch;
  int tc = blockIdx.x * 64, tr = blockIdx.y * 64;
  int t = threadIdx.x;
  int rr = t >> 3;
  int c8 = (t & 7) * 8;
#pragma unroll
  for (int i = 0; i < 2; ++i) {
    int r = rr + i * 32;
    uint4 v = *(const uint4*)(src + (long)(tr + r) * C + tc + c8);
    u16 vv[8]; *(uint4*)vv = v;
#pragma unroll
    for (int j = 0; j < 8; ++j) tile[r][c8 + j] = vv[j];
  }
  __syncthreads();
#pragma unroll
  for (int i = 0; i < 2; ++i) {
    int a = rr + i * 32;
    u16 vv[8];
#pragma unroll
    for (int j = 0; j < 8; ++j) vv[j] = tile[c8 + j][a];
    *(uint4*)(dst + (long)(tc + a) * R + tr + c8) = *(uint4*)vv;
  }
}

// ---------------- rope table: [2048][16] float2(cos,sin)
__global__ void rope_table_k(float2* __restrict__ tab) {
  int i = blockIdx.x * 256 + threadIdx.x;
  if (i >= 2048 * 16) return;
  int t = i >> 4, f = i & 15;
  float invf = exp2f(-(float)f * (13.287712379549449f / 16.0f));
  float th = (float)t * invf;
  float s, c;
  sincosf(th, &s, &c);
  tab[i] = make_float2(c, s);
}

// ---------------- rope apply, in place on bf16 Q,K [bh][t][64]; Q scaled 1/8
__global__ __launch_bounds__(256) void rope_apply_k(u16* __restrict__ Qg,
                                                    u16* __restrict__ Kg,
                                                    const float2* __restrict__ tab) {
  long tid = (long)blockIdx.x * 256 + threadIdx.x;
  int j = (int)(tid & 7);
  long row = tid >> 3;
  int t = (int)(row & 2047);
  int d0 = j * 4;
  u16* qp = Qg + row * 64;
  u16* kp = Kg + row * 64;
  u16 a1[4], a2[4], b1[4], b2[4];
  *(ushort4*)a1 = *(ushort4*)(qp + d0);
  *(ushort4*)a2 = *(ushort4*)(qp + d0 + 32);
  *(ushort4*)b1 = *(ushort4*)(kp + d0);
  *(ushort4*)b2 = *(ushort4*)(kp + d0 + 32);
  const float2* tp = tab + t * 16 + (d0 & 15);
#pragma unroll
  for (int i = 0; i < 4; ++i) {
    float2 cs = tp[i];
    float x1 = b2f(a1[i]), x2 = b2f(a2[i]);
    float y1 = b2f(b1[i]), y2 = b2f(b2[i]);
    a1[i] = f2b((x1 * cs.x - x2 * cs.y) * 0.125f);
    a2[i] = f2b((x2 * cs.x + x1 * cs.y) * 0.125f);
    b1[i] = f2b(y1 * cs.x - y2 * cs.y);
    b2[i] = f2b(y2 * cs.x + y1 * cs.y);
  }
  *(ushort4*)(qp + d0) = *(ushort4*)a1;
  *(ushort4*)(qp + d0 + 32) = *(ushort4*)a2;
  *(ushort4*)(kp + d0) = *(ushort4*)b1;
  *(ushort4*)(kp + d0 + 32) = *(ushort4*)b2;
}

// ---------------- GEMM: C = A @ Bt^T + bias, reg-staged LDS, bf16 MFMA.
// MODE=1: A = fp32 (x), scatter bf16 qkv -> out base, +8388608 per q/k/v.
// MODE=0: A = bf16, out = fp32 [M][N] (bf16-rounded values).
template <int MODE>
__global__ __launch_bounds__(256) void gemm_k(const void* __restrict__ Av,
                                              const u16* __restrict__ Bt,
                                              const float* __restrict__ bias,
                                              void* __restrict__ outv,
                                              int M, int N, int K) {
  __shared__ u16 As[128 * 40];  // [128][40]: 80B row stride, 16B-aligned chunks
  __shared__ u16 Bs[128 * 40];
  int tid = threadIdx.x, wid = tid >> 6, lane = tid & 63;
  int wr = wid >> 1, wc = wid & 1;
  long m0 = (long)blockIdx.x * 128, n0 = (long)blockIdx.y * 128;
  int r = lane & 15, g = lane >> 4;
  long arow = m0 + wid * 32 + (lane >> 2);
  int acol = (lane & 3) * 8;
  const float* Agf = (const float*)Av + arow * (long)K + acol;
  const u16*   Agb = (const u16*)Av + arow * (long)K + acol;
  const u16* Bg = Bt + (n0 + wid * 32 + (lane >> 2)) * (long)K + acol;
  int lrow = wid * 32 + (lane >> 2);
  int lcol = acol;
  f32x4 acc[4][4] = {};
  int nk = K >> 5;
  for (int kt = 0; kt < nk; ++kt) {
    long ko = (long)kt * 32;
    uint4 a0, a1;
    if (MODE == 1) {
      f32x4 p0 = *(const f32x4*)(Agf + ko);
      f32x4 p1 = *(const f32x4*)(Agf + ko + 4);
      f32x4 p2 = *(const f32x4*)(Agf + ko + 16 * (long)K);
      f32x4 p3 = *(const f32x4*)(Agf + ko + 16 * (long)K + 4);
      u16 h0[8], h1[8];
#pragma unroll
      for (int j = 0; j < 4; ++j) {
        h0[j] = f2b(p0[j]); h0[4 + j] = f2b(p1[j]);
        h1[j] = f2b(p2[j]); h1[4 + j] = f2b(p3[j]);
      }
      a0 = *(uint4*)h0; a1 = *(uint4*)h1;
    } else {
      a0 = *(const uint4*)(Agb + ko);
      a1 = *(const uint4*)(Agb + ko + 16 * (long)K);
    }
    uint4 b0 = *(const uint4*)(Bg + ko);
    uint4 b1 = *(const uint4*)(Bg + ko + 16 * (long)K);
    __syncthreads();
    *(uint4*)&As[lrow * 40 + lcol] = a0;
    *(uint4*)&As[(lrow + 16) * 40 + lcol] = a1;
    *(uint4*)&Bs[lrow * 40 + lcol] = b0;
    *(uint4*)&Bs[(lrow + 16) * 40 + lcol] = b1;
    __syncthreads();
    bf16x8 af[4], bfr[4];
#pragma unroll
    for (int mt = 0; mt < 4; ++mt)
      af[mt] = *(const bf16x8*)&As[(wr * 64 + mt * 16 + r) * 40 + g * 8];
#pragma unroll
    for (int nt = 0; nt < 4; ++nt)
      bfr[nt] = *(const bf16x8*)&Bs[(wc * 64 + nt * 16 + r) * 40 + g * 8];
#pragma unroll
    for (int mt = 0; mt < 4; ++mt)
#pragma unroll
      for (int nt = 0; nt < 4; ++nt)
        acc[mt][nt] = __builtin_amdgcn_mfma_f32_16x16x32_bf16(af[mt], bfr[nt], acc[mt][nt], 0, 0, 0);
  }
#pragma unroll
  for (int nt = 0; nt < 4; ++nt) {
    long col = n0 + wc * 64 + nt * 16 + r;
    float bv = bias[col];
#pragma unroll
    for (int mt = 0; mt < 4; ++mt) {
#pragma unroll
      for (int e = 0; e < 4; ++e) {
        long row = m0 + wr * 64 + mt * 16 + g * 4 + e;
        float v = acc[mt][nt][e] + bv;
        if (MODE == 0) {
          // bf16-rounded fp32: low mantissa zero (disambiguates bf16-read).
          ((float*)outv)[row * N + col] = b2f(f2b(v));
        } else {
          int which = (int)(col >> 10);
          int cc = (int)col & 1023;
          int hh = cc >> 6, dd = cc & 63;
          long bb = row >> 11;
          int tt = (int)row & 2047;
          ((u16*)outv)[(long)which * 8388608 + (((bb * 16 + hh) * 2048 + tt) << 6) + dd] = f2b(v);
        }
      }
    }
  }
}

// ---------------- flash attention, causal. Q,K: [bh][t][64] bf16, VgT: [bh][64][t]
__global__ __launch_bounds__(256) void attn_k(const u16* __restrict__ Qg,
                                              const u16* __restrict__ Kg,
                                              const u16* __restrict__ VgT,
                                              u16* __restrict__ Y) {
  __shared__ u16 Ks[64 * 72];
  __shared__ u16 Vt[64 * 72];
  __shared__ u16 Ps[4 * 16 * 72];
  int qt = 31 - blockIdx.x;
  int bh = blockIdx.y;
  int b = bh >> 4, h = bh & 15;
  long base = (long)bh * 2048 * 64;
  int tid = threadIdx.x, wid = tid >> 6, lane = tid & 63;
  int r = lane & 15, g = lane >> 4;
  int qw = qt * 64 + wid * 16;
  bf16x8 qf[2];
#pragma unroll
  for (int kk = 0; kk < 2; ++kk)
    qf[kk] = *(const bf16x8*)&Qg[base + (long)(qw + r) * 64 + kk * 32 + g * 8];
  f32x4 acc[4] = {};
  float mrow[4], lrowv[4];
#pragma unroll
  for (int e = 0; e < 4; ++e) { mrow[e] = -INFINITY; lrowv[e] = 0.f; }
  u16* Pw = Ps + wid * (16 * 72);
  for (int kt = 0; kt <= qt; ++kt) {
    __syncthreads();
#pragma unroll
    for (int uu = 0; uu < 2; ++uu) {
      int u = tid + uu * 256;
      int row = u >> 3, ch = u & 7;
      uint4 v = *(const uint4*)&Kg[base + (long)(kt * 64 + row) * 64 + ch * 8];
      *(uint4*)&Ks[row * 72 + ch * 8] = v;
      uint4 w = *(const uint4*)&VgT[base + (long)row * 2048 + kt * 64 + ch * 8];
      *(uint4*)&Vt[row * 72 + ch * 8] = w;
    }
    __syncthreads();
    f32x4 s[4];
#pragma unroll
    for (int ct = 0; ct < 4; ++ct) {
      f32x4 z = {};
#pragma unroll
      for (int kk = 0; kk < 2; ++kk) {
        bf16x8 kf = *(const bf16x8*)&Ks[(ct * 16 + r) * 72 + g * 8 + kk * 32];
        z = __builtin_amdgcn_mfma_f32_16x16x32_bf16(qf[kk], kf, z, 0, 0, 0);
      }
      s[ct] = z;
    }
    if (kt == qt) {
#pragma unroll
      for (int ct = 0; ct < 4; ++ct)
#pragma unroll
        for (int e = 0; e < 4; ++e) {
          int qrow = qw + g * 4 + e;
          int kv = kt * 64 + ct * 16 + r;
          if (kv > qrow) s[ct][e] = -INFINITY;
        }
    }
    float pm[4];
#pragma unroll
    for (int e = 0; e < 4; ++e)
      pm[e] = fmaxf(fmaxf(s[0][e], s[1][e]), fmaxf(s[2][e], s[3][e]));
#pragma unroll
    for (int msk = 1; msk < 16; msk <<= 1)
#pragma unroll
      for (int e = 0; e < 4; ++e) pm[e] = fmaxf(pm[e], __shfl_xor(pm[e], msk));
    float alpha[4];
#pragma unroll
    for (int e = 0; e < 4; ++e) {
      float mn = fmaxf(mrow[e], pm[e]);
      alpha[e] = exp2f((mrow[e] - mn) * LOG2E);
      mrow[e] = mn;
    }
    float rs[4] = {0.f, 0.f, 0.f, 0.f};
#pragma unroll
    for (int ct = 0; ct < 4; ++ct)
#pragma unroll
      for (int e = 0; e < 4; ++e) {
        float p = exp2f((s[ct][e] - mrow[e]) * LOG2E);
        s[ct][e] = p;
        rs[e] += p;
      }
#pragma unroll
    for (int msk = 1; msk < 16; msk <<= 1)
#pragma unroll
      for (int e = 0; e < 4; ++e) rs[e] += __shfl_xor(rs[e], msk);
#pragma unroll
    for (int e = 0; e < 4; ++e) lrowv[e] = lrowv[e] * alpha[e] + rs[e];
#pragma unroll
    for (int dt = 0; dt < 4; ++dt)
#pragma unroll
      for (int e = 0; e < 4; ++e) acc[dt][e] *= alpha[e];
#pragma unroll
    for (int ct = 0; ct < 4; ++ct)
#pragma unroll
      for (int e = 0; e < 4; ++e)
        Pw[(g * 4 + e) * 72 + ct * 16 + r] = f2b(s[ct][e]);
    bf16x8 pa[2];
#pragma unroll
    for (int kk = 0; kk < 2; ++kk)
      pa[kk] = *(const bf16x8*)&Pw[r * 72 + kk * 32 + g * 8];
#pragma unroll
    for (int dt = 0; dt < 4; ++dt) {
#pragma unroll
      for (int kk = 0; kk < 2; ++kk) {
        bf16x8 vf = *(const bf16x8*)&Vt[(dt * 16 + r) * 72 + g * 8 + kk * 32];
        acc[dt] = __builtin_amdgcn_mfma_f32_16x16x32_bf16(pa[kk], vf, acc[dt], 0, 0, 0);
      }
    }
  }
#pragma unroll
  for (int dt = 0; dt < 4; ++dt)
#pragma unroll
    for (int e = 0; e < 4; ++e) {
      int qrow = qw + g * 4 + e;
      float o = acc[dt][e] / lrowv[e];
      Y[((long)(b * 2048 + qrow)) * 1024 + h * 64 + dt * 16 + r] = f2b(o);
    }
}

extern "C" void kernel_launch(void* const* d_in, const int* in_sizes, int n_in,
                              void* d_out, int out_size, void* d_ws, size_t ws_size,
                              hipStream_t stream) {
  const float* x  = (const float*)d_in[0];
  const float* Wa = (const float*)d_in[1];
  const float* ba = (const float*)d_in[2];
  const float* Wp = (const float*)d_in[3];
  const float* bp = (const float*)d_in[4];

  if (ws_size < 67108864ULL) {  // need 64 MiB; sentinel absmax ~1e3 signals this
    sentinel_k<<<dim3((out_size + 255) / 256), 256, 0, stream>>>((u16*)d_out, out_size);
    return;
  }

  u16* ws  = (u16*)d_ws;
  u16* Qg  = ws;                           // [0, 8388608)
  u16* Kg  = ws + 8388608;                 // [8388608, 16777216)
  u16* Vg  = ws + 16777216;                // [16777216, 25165824)
  u16* Yb  = ws + 16777216;                // over dead Vg (after V-transpose)
  u16* WaT = ws + 25165824;                // bf16, dead after QKV GEMM
  float2* tab = (float2*)(ws + 28311552);  // dead after rope_apply
  u16* VgT = ws + 25165824;                // over dead WaT+tab
  u16* WpT = ws;                           // over dead Qg (after attn)

  transpose_f2b_k<<<dim3(48, 16), 256, 0, stream>>>(Wa, WaT, 1024, 3072);
  rope_table_k<<<dim3(128), 256, 0, stream>>>(tab);
  gemm_k<1><<<dim3(64, 24), 256, 0, stream>>>(x, WaT, ba, Qg, 8192, 3072, 1024);
  rope_apply_k<<<dim3(4096), 256, 0, stream>>>(Qg, Kg, tab);
  transpose_b_k<<<dim3(1, 32, 64), 256, 0, stream>>>(Vg, VgT, 2048, 64, 131072L, 131072L);
  attn_k<<<dim3(32, 64), 256, 0, stream>>>(Qg, Kg, VgT, Yb);
  transpose_f2b_k<<<dim3(16, 16), 256, 0, stream>>>(Wp, WpT, 1024, 1024);
  gemm_k<0><<<dim3(64, 8), 256, 0, stream>>>(Yb, WpT, bp, d_out, 8192, 1024, 1024);
}

// Round 5
// 224.895 us; speedup vs baseline: 1.8637x; 1.8637x over previous
//
#include <hip/hip_runtime.h>
#include <math.h>

// CausalSelfAttention: B=4 T=2048 C=1024 H=16 hd=64. fp32 I/O, bf16 MFMA internals.
// R5: attn rewritten to swapped-QK 32x32 MFMA + in-register softmax (m214-style):
//   S^T = mfma(K,Q) -> lane owns one q-row (q=lane&31), k via crow(reg,hi).
//   Per-lane scalar max/sum (tree + 1 shfl_xor(32)), defer-max rescale (T13),
//   exp2-domain scores (log2e folded into Q prescale), P->PV via quad exchange.
//
// ws (u16 elems), peak 33,554,432 u16 = 64 MiB:
//   [0,        8388608)  Qg          ... after attn: WpT over dead Qg
//   [8388608, 16777216)  Kg
//   [16777216,25165824)  Vg          ... after V-transpose: Yb over dead Vg
//   [25165824,28311552)  WaT (bf16)  ... dead after QKV GEMM
//   [28311552,28442624)  rope tab    ... dead after rope_apply
//   [25165824,33554432)  VgT (over dead WaT+tab)

typedef unsigned short u16;
typedef __bf16 bf16x8 __attribute__((ext_vector_type(8)));
typedef float f32x4 __attribute__((ext_vector_type(4)));
typedef float f32x16 __attribute__((ext_vector_type(16)));

__device__ __forceinline__ float b2f(u16 x) {
  union { unsigned u; float f; } c; c.u = ((unsigned)x) << 16; return c.f;
}
__device__ __forceinline__ u16 f2b(float f) {
  union { __bf16 h; u16 u; } c; c.h = (__bf16)f; return c.u;
}

// ---------------- sentinel fill (ws too small signal)
__global__ __launch_bounds__(256) void sentinel_k(u16* __restrict__ out, int n) {
  int i = blockIdx.x * 256 + threadIdx.x;
  if (i < n) out[i] = 0x4480;  // bf16 1024.0
}

// ---------------- transpose fp32 src[R][C] -> bf16 dst[C][R], 64x64 tiles
__global__ __launch_bounds__(256) void transpose_f2b_k(const float* __restrict__ src,
                                                       u16* __restrict__ dst,
                                                       int R, int C) {
  __shared__ u16 tile[64][65];
  int tc = blockIdx.x * 64, tr = blockIdx.y * 64;
  int t = threadIdx.x;
  int rr = t >> 3;
  int c8 = (t & 7) * 8;
#pragma unroll
  for (int i = 0; i < 2; ++i) {
    int r = rr + i * 32;
    f32x4 p0 = *(const f32x4*)(src + (long)(tr + r) * C + tc + c8);
    f32x4 p1 = *(const f32x4*)(src + (long)(tr + r) * C + tc + c8 + 4);
#pragma unroll
    for (int j = 0; j < 4; ++j) {
      tile[r][c8 + j] = f2b(p0[j]);
      tile[r][c8 + 4 + j] = f2b(p1[j]);
    }
  }
  __syncthreads();
#pragma unroll
  for (int i = 0; i < 2; ++i) {
    int a = rr + i * 32;
    u16 vv[8];
#pragma unroll
    for (int j = 0; j < 8; ++j) vv[j] = tile[c8 + j][a];
    *(uint4*)(dst + (long)(tc + a) * R + tr + c8) = *(uint4*)vv;
  }
}

// ---------------- transpose bf16 src[R][C] -> bf16 dst[C][R], batched via z
__global__ __launch_bounds__(256) void transpose_b_k(const u16* __restrict__ src,
                                                     u16* __restrict__ dst,
                                                     int R, int C,
                                                     long sBatch, long dBatch) {
  __shared__ u16 tile[64][65];
  src += (long)blockIdx.z * sBatch;
  dst += (long)blockIdx.z * dBatch;
  int tc = blockIdx.x * 64, tr = blockIdx.y * 64;
  int t = threadIdx.x;
  int rr = t >> 3;
  int c8 = (t & 7) * 8;
#pragma unroll
  for (int i = 0; i < 2; ++i) {
    int r = rr + i * 32;
    uint4 v = *(const uint4*)(src + (long)(tr + r) * C + tc + c8);
    u16 vv[8]; *(uint4*)vv = v;
#pragma unroll
    for (int j = 0; j < 8; ++j) tile[r][c8 + j] = vv[j];
  }
  __syncthreads();
#pragma unroll
  for (int i = 0; i < 2; ++i) {
    int a = rr + i * 32;
    u16 vv[8];
#pragma unroll
    for (int j = 0; j < 8; ++j) vv[j] = tile[c8 + j][a];
    *(uint4*)(dst + (long)(tc + a) * R + tr + c8) = *(uint4*)vv;
  }
}

// ---------------- rope table: [2048][16] float2(cos,sin)
__global__ void rope_table_k(float2* __restrict__ tab) {
  int i = blockIdx.x * 256 + threadIdx.x;
  if (i >= 2048 * 16) return;
  int t = i >> 4, f = i & 15;
  float invf = exp2f(-(float)f * (13.287712379549449f / 16.0f));
  float th = (float)t * invf;
  float s, c;
  sincosf(th, &s, &c);
  tab[i] = make_float2(c, s);
}

// ---------------- rope apply, in place on bf16 Q,K [bh][t][64]
// Q scaled by (1/8)*log2(e): puts QK^T scores in exp2 domain for attn.
__global__ __launch_bounds__(256) void rope_apply_k(u16* __restrict__ Qg,
                                                    u16* __restrict__ Kg,
                                                    const float2* __restrict__ tab) {
  const float QSCALE = 0.18033688501389543f;  // 0.125 * log2(e)
  long tid = (long)blockIdx.x * 256 + threadIdx.x;
  int j = (int)(tid & 7);
  long row = tid >> 3;
  int t = (int)(row & 2047);
  int d0 = j * 4;
  u16* qp = Qg + row * 64;
  u16* kp = Kg + row * 64;
  u16 a1[4], a2[4], b1[4], b2[4];
  *(ushort4*)a1 = *(ushort4*)(qp + d0);
  *(ushort4*)a2 = *(ushort4*)(qp + d0 + 32);
  *(ushort4*)b1 = *(ushort4*)(kp + d0);
  *(ushort4*)b2 = *(ushort4*)(kp + d0 + 32);
  const float2* tp = tab + t * 16 + (d0 & 15);
#pragma unroll
  for (int i = 0; i < 4; ++i) {
    float2 cs = tp[i];
    float x1 = b2f(a1[i]), x2 = b2f(a2[i]);
    float y1 = b2f(b1[i]), y2 = b2f(b2[i]);
    a1[i] = f2b((x1 * cs.x - x2 * cs.y) * QSCALE);
    a2[i] = f2b((x2 * cs.x + x1 * cs.y) * QSCALE);
    b1[i] = f2b(y1 * cs.x - y2 * cs.y);
    b2[i] = f2b(y2 * cs.x + y1 * cs.y);
  }
  *(ushort4*)(qp + d0) = *(ushort4*)a1;
  *(ushort4*)(qp + d0 + 32) = *(ushort4*)a2;
  *(ushort4*)(kp + d0) = *(ushort4*)b1;
  *(ushort4*)(kp + d0 + 32) = *(ushort4*)b2;
}

// ---------------- GEMM: C = A @ Bt^T + bias, reg-staged LDS, bf16 MFMA.
// MODE=1: A = fp32 (x), scatter bf16 qkv -> out base, +8388608 per q/k/v.
// MODE=0: A = bf16, out = fp32 [M][N].
template <int MODE>
__global__ __launch_bounds__(256) void gemm_k(const void* __restrict__ Av,
                                              const u16* __restrict__ Bt,
                                              const float* __restrict__ bias,
                                              void* __restrict__ outv,
                                              int M, int N, int K) {
  __shared__ u16 As[128 * 40];
  __shared__ u16 Bs[128 * 40];
  int tid = threadIdx.x, wid = tid >> 6, lane = tid & 63;
  int wr = wid >> 1, wc = wid & 1;
  long m0 = (long)blockIdx.x * 128, n0 = (long)blockIdx.y * 128;
  int r = lane & 15, g = lane >> 4;
  long arow = m0 + wid * 32 + (lane >> 2);
  int acol = (lane & 3) * 8;
  const float* Agf = (const float*)Av + arow * (long)K + acol;
  const u16*   Agb = (const u16*)Av + arow * (long)K + acol;
  const u16* Bg = Bt + (n0 + wid * 32 + (lane >> 2)) * (long)K + acol;
  int lrow = wid * 32 + (lane >> 2);
  int lcol = acol;
  f32x4 acc[4][4] = {};
  int nk = K >> 5;
  for (int kt = 0; kt < nk; ++kt) {
    long ko = (long)kt * 32;
    uint4 a0, a1;
    if (MODE == 1) {
      f32x4 p0 = *(const f32x4*)(Agf + ko);
      f32x4 p1 = *(const f32x4*)(Agf + ko + 4);
      f32x4 p2 = *(const f32x4*)(Agf + ko + 16 * (long)K);
      f32x4 p3 = *(const f32x4*)(Agf + ko + 16 * (long)K + 4);
      u16 h0[8], h1[8];
#pragma unroll
      for (int j = 0; j < 4; ++j) {
        h0[j] = f2b(p0[j]); h0[4 + j] = f2b(p1[j]);
        h1[j] = f2b(p2[j]); h1[4 + j] = f2b(p3[j]);
      }
      a0 = *(uint4*)h0; a1 = *(uint4*)h1;
    } else {
      a0 = *(const uint4*)(Agb + ko);
      a1 = *(const uint4*)(Agb + ko + 16 * (long)K);
    }
    uint4 b0 = *(const uint4*)(Bg + ko);
    uint4 b1 = *(const uint4*)(Bg + ko + 16 * (long)K);
    __syncthreads();
    *(uint4*)&As[lrow * 40 + lcol] = a0;
    *(uint4*)&As[(lrow + 16) * 40 + lcol] = a1;
    *(uint4*)&Bs[lrow * 40 + lcol] = b0;
    *(uint4*)&Bs[(lrow + 16) * 40 + lcol] = b1;
    __syncthreads();
    bf16x8 af[4], bfr[4];
#pragma unroll
    for (int mt = 0; mt < 4; ++mt)
      af[mt] = *(const bf16x8*)&As[(wr * 64 + mt * 16 + r) * 40 + g * 8];
#pragma unroll
    for (int nt = 0; nt < 4; ++nt)
      bfr[nt] = *(const bf16x8*)&Bs[(wc * 64 + nt * 16 + r) * 40 + g * 8];
#pragma unroll
    for (int mt = 0; mt < 4; ++mt)
#pragma unroll
      for (int nt = 0; nt < 4; ++nt)
        acc[mt][nt] = __builtin_amdgcn_mfma_f32_16x16x32_bf16(af[mt], bfr[nt], acc[mt][nt], 0, 0, 0);
  }
#pragma unroll
  for (int nt = 0; nt < 4; ++nt) {
    long col = n0 + wc * 64 + nt * 16 + r;
    float bv = bias[col];
#pragma unroll
    for (int mt = 0; mt < 4; ++mt) {
#pragma unroll
      for (int e = 0; e < 4; ++e) {
        long row = m0 + wr * 64 + mt * 16 + g * 4 + e;
        float v = acc[mt][nt][e] + bv;
        if (MODE == 0) {
          ((float*)outv)[row * N + col] = v;
        } else {
          int which = (int)(col >> 10);
          int cc = (int)col & 1023;
          int hh = cc >> 6, dd = cc & 63;
          long bb = row >> 11;
          int tt = (int)row & 2047;
          ((u16*)outv)[(long)which * 8388608 + (((bb * 16 + hh) * 2048 + tt) << 6) + dd] = f2b(v);
        }
      }
    }
  }
}

// ---------------- flash attention v2: swapped-QK 32x32, in-register softmax.
// Q,K: [bh][t][64] bf16 (Q pre-scaled by log2e/8), VgT: [bh][64][t].
// Block: 4 waves x 32 q-rows = 128 q. Grid: (bh=64, qb=16).
// Score layout (C of mfma(K,Q)): q = lane&31, k = ct*32 + (reg&3)+8*(reg>>2)+4*hi.
__global__ __launch_bounds__(256) void attn_k(const u16* __restrict__ Qg,
                                              const u16* __restrict__ Kg,
                                              const u16* __restrict__ VgT,
                                              u16* __restrict__ Y) {
  __shared__ u16 Ks[64 * 72];  // [kv 64][d 64] +8 pad (144B stride: b128 bank-floor)
  __shared__ u16 Vt[64 * 72];  // [d 64][kv 64] +8 pad
  int qb = 15 - (int)blockIdx.y;  // long blocks first
  int bh = blockIdx.x;
  int b = bh >> 4, h = bh & 15;
  long base = (long)bh * (2048 * 64);
  int tid = threadIdx.x, wid = tid >> 6;
  int lane = tid & 63, l31 = lane & 31, hi = lane >> 5;
  int q0w = qb * 128 + wid * 32;
  int myEnd = (q0w + 31) >> 6;   // last kv tile this wave needs (diagonal)
  int ktMax = 2 * qb + 1;        // last kv tile any wave in block needs
  bf16x8 qf[4];
  {
    const u16* qp = Qg + base + (long)(q0w + l31) * 64 + hi * 8;
#pragma unroll
    for (int s = 0; s < 4; ++s) qf[s] = *(const bf16x8*)(qp + s * 16);
  }
  f32x16 acc0 = {}, acc1 = {};   // O[q=crow][d=l31 (+32)]
  float mrow = -INFINITY, lrow = 0.f;
  for (int kt = 0; kt <= ktMax; ++kt) {
    __syncthreads();
#pragma unroll
    for (int uu = 0; uu < 2; ++uu) {
      int u = tid + uu * 256;
      int row = u >> 3, c4 = (u & 7) * 8;
      *(uint4*)&Ks[row * 72 + c4] =
          *(const uint4*)&Kg[base + (long)(kt * 64 + row) * 64 + c4];
      *(uint4*)&Vt[row * 72 + c4] =
          *(const uint4*)&VgT[base + (long)row * 2048 + kt * 64 + c4];
    }
    __syncthreads();
    if (kt > myEnd) continue;
    // S^T = K @ Q^T : st[ct] covers k = ct*32..+31 for q = l31
    f32x16 st[2];
#pragma unroll
    for (int ct = 0; ct < 2; ++ct) {
      f32x16 z = {};
#pragma unroll
      for (int s = 0; s < 4; ++s) {
        bf16x8 kf = *(const bf16x8*)&Ks[(ct * 32 + l31) * 72 + s * 16 + hi * 8];
        z = __builtin_amdgcn_mfma_f32_32x32x16_bf16(kf, qf[s], z, 0, 0, 0);
      }
      st[ct] = z;
    }
    if (kt == myEnd) {  // causal mask (only diagonal tile needs it)
      int qg = q0w + l31;
#pragma unroll
      for (int ct = 0; ct < 2; ++ct)
#pragma unroll
        for (int reg = 0; reg < 16; ++reg) {
          int kg = kt * 64 + ct * 32 + (reg & 3) + 8 * (reg >> 2) + 4 * hi;
          if (kg > qg) st[ct][reg] = -INFINITY;
        }
    }
    // row max: tree over 32 in-reg + cross-half shfl
    float t8[8];
#pragma unroll
    for (int i = 0; i < 8; ++i)
      t8[i] = fmaxf(fmaxf(st[0][i], st[0][i + 8]), fmaxf(st[1][i], st[1][i + 8]));
#pragma unroll
    for (int i = 0; i < 4; ++i) t8[i] = fmaxf(t8[i], t8[i + 4]);
    float pm = fmaxf(fmaxf(t8[0], t8[1]), fmaxf(t8[2], t8[3]));
    pm = fmaxf(pm, __shfl_xor(pm, 32));
    // defer-max (T13): rescale only when max grew by > 8 (base-2 units)
    if (__any(pm > mrow + 8.0f)) {
      float mn = fmaxf(mrow, pm);
      float alpha = exp2f(mrow - mn);
      mrow = mn;
      lrow *= alpha;
#pragma unroll
      for (int reg = 0; reg < 16; ++reg) {
        float aB = __shfl(alpha, (reg & 3) + 8 * (reg >> 2) + 4 * hi);
        acc0[reg] *= aB;
        acc1[reg] *= aB;
      }
    }
    // p = exp2(s - mrow); row sum
    float s8[8];
#pragma unroll
    for (int i = 0; i < 8; ++i) s8[i] = 0.f;
#pragma unroll
    for (int ct = 0; ct < 2; ++ct)
#pragma unroll
      for (int reg = 0; reg < 16; ++reg) {
        float p = exp2f(st[ct][reg] - mrow);
        st[ct][reg] = p;
        s8[reg & 7] += p;
      }
#pragma unroll
    for (int i = 0; i < 4; ++i) s8[i] += s8[i + 4];
    float rs = (s8[0] + s8[1]) + (s8[2] + s8[3]);
    rs += __shfl_xor(rs, 32);
    lrow += rs;
    // PV: quad-exchange P into A-frag slots (k = ks*16 + hi*8 + j), then mfma
#pragma unroll
    for (int ct = 0; ct < 2; ++ct) {
      bf16x8 af[2];
#pragma unroll
      for (int ks = 0; ks < 2; ++ks) {
#pragma unroll
        for (int u = 0; u < 4; ++u) {
          float sendv = hi ? st[ct][8 * ks + u] : st[ct][8 * ks + 4 + u];
          float keepv = hi ? st[ct][8 * ks + 4 + u] : st[ct][8 * ks + u];
          float rcv = __shfl_xor(sendv, 32);
          af[ks][u] = (__bf16)(hi ? rcv : keepv);
          af[ks][4 + u] = (__bf16)(hi ? keepv : rcv);
        }
      }
#pragma unroll
      for (int ks = 0; ks < 2; ++ks) {
        bf16x8 vf0 = *(const bf16x8*)&Vt[l31 * 72 + ct * 32 + ks * 16 + hi * 8];
        bf16x8 vf1 = *(const bf16x8*)&Vt[(32 + l31) * 72 + ct * 32 + ks * 16 + hi * 8];
        acc0 = __builtin_amdgcn_mfma_f32_32x32x16_bf16(af[ks], vf0, acc0, 0, 0, 0);
        acc1 = __builtin_amdgcn_mfma_f32_32x32x16_bf16(af[ks], vf1, acc1, 0, 0, 0);
      }
    }
  }
  float rinv = 1.0f / lrow;
#pragma unroll
  for (int reg = 0; reg < 16; ++reg) {
    int crow = (reg & 3) + 8 * (reg >> 2) + 4 * hi;
    float rB = __shfl(rinv, crow);
    long orow = (long)(b * 2048 + q0w + crow) * 1024 + h * 64;
    Y[orow + l31] = f2b(acc0[reg] * rB);
    Y[orow + 32 + l31] = f2b(acc1[reg] * rB);
  }
}

extern "C" void kernel_launch(void* const* d_in, const int* in_sizes, int n_in,
                              void* d_out, int out_size, void* d_ws, size_t ws_size,
                              hipStream_t stream) {
  const float* x  = (const float*)d_in[0];
  const float* Wa = (const float*)d_in[1];
  const float* ba = (const float*)d_in[2];
  const float* Wp = (const float*)d_in[3];
  const float* bp = (const float*)d_in[4];

  if (ws_size < 67108864ULL) {
    sentinel_k<<<dim3((out_size + 255) / 256), 256, 0, stream>>>((u16*)d_out, out_size);
    return;
  }

  u16* ws  = (u16*)d_ws;
  u16* Qg  = ws;                           // [0, 8388608)
  u16* Kg  = ws + 8388608;                 // [8388608, 16777216)
  u16* Vg  = ws + 16777216;                // [16777216, 25165824)
  u16* Yb  = ws + 16777216;                // over dead Vg (after V-transpose)
  u16* WaT = ws + 25165824;                // bf16, dead after QKV GEMM
  float2* tab = (float2*)(ws + 28311552);  // dead after rope_apply
  u16* VgT = ws + 25165824;                // over dead WaT+tab
  u16* WpT = ws;                           // over dead Qg (after attn)

  transpose_f2b_k<<<dim3(48, 16), 256, 0, stream>>>(Wa, WaT, 1024, 3072);
  rope_table_k<<<dim3(128), 256, 0, stream>>>(tab);
  gemm_k<1><<<dim3(64, 24), 256, 0, stream>>>(x, WaT, ba, Qg, 8192, 3072, 1024);
  rope_apply_k<<<dim3(4096), 256, 0, stream>>>(Qg, Kg, tab);
  transpose_b_k<<<dim3(1, 32, 64), 256, 0, stream>>>(Vg, VgT, 2048, 64, 131072L, 131072L);
  attn_k<<<dim3(64, 16), 256, 0, stream>>>(Qg, Kg, VgT, Yb);
  transpose_f2b_k<<<dim3(16, 16), 256, 0, stream>>>(Wp, WpT, 1024, 1024);
  gemm_k<0><<<dim3(64, 8), 256, 0, stream>>>(Yb, WpT, bp, d_out, 8192, 1024, 1024);
}

// Round 6
// 211.244 us; speedup vs baseline: 1.9841x; 1.0646x over previous
//
#include <hip/hip_runtime.h>
#include <math.h>

// CausalSelfAttention: B=4 T=2048 C=1024 H=16 hd=64. fp32 I/O, bf16 MFMA internals.
// R6: (1) attn strip-pairing for causal load balance: wave owns strips s and 63-s
//     (2) RoPE fused into QKV GEMM epilogue (rope_apply pass deleted)
//     (3) proj GEMM via global_load_lds (m97 pattern)
//
// ws (u16 elems), peak 33,554,432 u16 = 64 MiB:
//   [0,        8388608)  Qg          ... after attn: WpT over dead Qg
//   [8388608, 16777216)  Kg
//   [16777216,25165824)  Vg          ... after V-transpose: Yb over dead Vg
//   [25165824,28311552)  WaT (bf16)  ... dead after QKV GEMM
//   [28311552,28442624)  rope tab    ... dead after QKV GEMM
//   [25165824,33554432)  VgT (over dead WaT+tab)

typedef unsigned short u16;
typedef __bf16 bf16x8 __attribute__((ext_vector_type(8)));
typedef float f32x4 __attribute__((ext_vector_type(4)));
typedef float f32x16 __attribute__((ext_vector_type(16)));

#define QSCALE 0.18033688501389543f  // 0.125 * log2(e)

__device__ __forceinline__ float b2f(u16 x) {
  union { unsigned u; float f; } c; c.u = ((unsigned)x) << 16; return c.f;
}
__device__ __forceinline__ u16 f2b(float f) {
  union { __bf16 h; u16 u; } c; c.h = (__bf16)f; return c.u;
}

#define GLOAD16(gp, lp)                                                  \
  __builtin_amdgcn_global_load_lds(                                      \
      (const __attribute__((address_space(1))) unsigned int*)(gp),       \
      (__attribute__((address_space(3))) unsigned int*)(lp), 16, 0, 0)

// ---------------- sentinel fill (ws too small signal)
__global__ __launch_bounds__(256) void sentinel_k(u16* __restrict__ out, int n) {
  int i = blockIdx.x * 256 + threadIdx.x;
  if (i < n) out[i] = 0x4480;  // bf16 1024.0
}

// ---------------- transpose fp32 src[R][C] -> bf16 dst[C][R], 64x64 tiles
__global__ __launch_bounds__(256) void transpose_f2b_k(const float* __restrict__ src,
                                                       u16* __restrict__ dst,
                                                       int R, int C) {
  __shared__ u16 tile[64][65];
  int tc = blockIdx.x * 64, tr = blockIdx.y * 64;
  int t = threadIdx.x;
  int rr = t >> 3;
  int c8 = (t & 7) * 8;
#pragma unroll
  for (int i = 0; i < 2; ++i) {
    int r = rr + i * 32;
    f32x4 p0 = *(const f32x4*)(src + (long)(tr + r) * C + tc + c8);
    f32x4 p1 = *(const f32x4*)(src + (long)(tr + r) * C + tc + c8 + 4);
#pragma unroll
    for (int j = 0; j < 4; ++j) {
      tile[r][c8 + j] = f2b(p0[j]);
      tile[r][c8 + 4 + j] = f2b(p1[j]);
    }
  }
  __syncthreads();
#pragma unroll
  for (int i = 0; i < 2; ++i) {
    int a = rr + i * 32;
    u16 vv[8];
#pragma unroll
    for (int j = 0; j < 8; ++j) vv[j] = tile[c8 + j][a];
    *(uint4*)(dst + (long)(tc + a) * R + tr + c8) = *(uint4*)vv;
  }
}

// ---------------- transpose bf16 src[R][C] -> bf16 dst[C][R], batched via z
__global__ __launch_bounds__(256) void transpose_b_k(const u16* __restrict__ src,
                                                     u16* __restrict__ dst,
                                                     int R, int C,
                                                     long sBatch, long dBatch) {
  __shared__ u16 tile[64][65];
  src += (long)blockIdx.z * sBatch;
  dst += (long)blockIdx.z * dBatch;
  int tc = blockIdx.x * 64, tr = blockIdx.y * 64;
  int t = threadIdx.x;
  int rr = t >> 3;
  int c8 = (t & 7) * 8;
#pragma unroll
  for (int i = 0; i < 2; ++i) {
    int r = rr + i * 32;
    uint4 v = *(const uint4*)(src + (long)(tr + r) * C + tc + c8);
    u16 vv[8]; *(uint4*)vv = v;
#pragma unroll
    for (int j = 0; j < 8; ++j) tile[r][c8 + j] = vv[j];
  }
  __syncthreads();
#pragma unroll
  for (int i = 0; i < 2; ++i) {
    int a = rr + i * 32;
    u16 vv[8];
#pragma unroll
    for (int j = 0; j < 8; ++j) vv[j] = tile[c8 + j][a];
    *(uint4*)(dst + (long)(tc + a) * R + tr + c8) = *(uint4*)vv;
  }
}

// ---------------- rope table: [2048][16] float2(cos,sin)
__global__ void rope_table_k(float2* __restrict__ tab) {
  int i = blockIdx.x * 256 + threadIdx.x;
  if (i >= 2048 * 16) return;
  int t = i >> 4, f = i & 15;
  float invf = exp2f(-(float)f * (13.287712379549449f / 16.0f));
  float th = (float)t * invf;
  float s, c;
  sincosf(th, &s, &c);
  tab[i] = make_float2(c, s);
}

// ---------------- QKV GEMM: qkv = x @ WaT^T + ba, RoPE fused in epilogue.
// A = fp32 x [8192][1024], Bt = bf16 WaT [3072][1024]. Scatter bf16 to
// out + which*8388608, layout [bh][t][64]. Q scaled by QSCALE (log2e/8).
__global__ __launch_bounds__(256) void gemm_qkv_k(const float* __restrict__ A,
                                                  const u16* __restrict__ Bt,
                                                  const float* __restrict__ bias,
                                                  const float2* __restrict__ tab,
                                                  u16* __restrict__ out,
                                                  int M, int N, int K) {
  __shared__ u16 As[128 * 40];
  __shared__ u16 Bs[128 * 40];
  int tid = threadIdx.x, wid = tid >> 6, lane = tid & 63;
  int wr = wid >> 1, wc = wid & 1;
  long m0 = (long)blockIdx.x * 128, n0 = (long)blockIdx.y * 128;
  int r = lane & 15, g = lane >> 4;
  long arow = m0 + wid * 32 + (lane >> 2);
  int acol = (lane & 3) * 8;
  const float* Agf = A + arow * (long)K + acol;
  const u16* Bg = Bt + (n0 + wid * 32 + (lane >> 2)) * (long)K + acol;
  int lrow = wid * 32 + (lane >> 2);
  int lcol = acol;
  f32x4 acc[4][4] = {};
  int nk = K >> 5;
  for (int kt = 0; kt < nk; ++kt) {
    long ko = (long)kt * 32;
    f32x4 p0 = *(const f32x4*)(Agf + ko);
    f32x4 p1 = *(const f32x4*)(Agf + ko + 4);
    f32x4 p2 = *(const f32x4*)(Agf + ko + 16 * (long)K);
    f32x4 p3 = *(const f32x4*)(Agf + ko + 16 * (long)K + 4);
    u16 h0[8], h1[8];
#pragma unroll
    for (int j = 0; j < 4; ++j) {
      h0[j] = f2b(p0[j]); h0[4 + j] = f2b(p1[j]);
      h1[j] = f2b(p2[j]); h1[4 + j] = f2b(p3[j]);
    }
    uint4 a0 = *(uint4*)h0, a1 = *(uint4*)h1;
    uint4 b0 = *(const uint4*)(Bg + ko);
    uint4 b1 = *(const uint4*)(Bg + ko + 16 * (long)K);
    __syncthreads();
    *(uint4*)&As[lrow * 40 + lcol] = a0;
    *(uint4*)&As[(lrow + 16) * 40 + lcol] = a1;
    *(uint4*)&Bs[lrow * 40 + lcol] = b0;
    *(uint4*)&Bs[(lrow + 16) * 40 + lcol] = b1;
    __syncthreads();
    bf16x8 af[4], bfr[4];
#pragma unroll
    for (int mt = 0; mt < 4; ++mt)
      af[mt] = *(const bf16x8*)&As[(wr * 64 + mt * 16 + r) * 40 + g * 8];
#pragma unroll
    for (int nt = 0; nt < 4; ++nt)
      bfr[nt] = *(const bf16x8*)&Bs[(wc * 64 + nt * 16 + r) * 40 + g * 8];
#pragma unroll
    for (int mt = 0; mt < 4; ++mt)
#pragma unroll
      for (int nt = 0; nt < 4; ++nt)
        acc[mt][nt] = __builtin_amdgcn_mfma_f32_16x16x32_bf16(af[mt], bfr[nt], acc[mt][nt], 0, 0, 0);
  }
  // epilogue: bias + RoPE (q,k) + scatter. which is block-uniform.
  int which = (int)(n0 >> 10);
  int hh = ((int)(n0 & 1023) >> 6) + wc;
  float bv[4];
#pragma unroll
  for (int nt = 0; nt < 4; ++nt) bv[nt] = bias[n0 + wc * 64 + nt * 16 + r];
#pragma unroll
  for (int mt = 0; mt < 4; ++mt) {
#pragma unroll
    for (int e = 0; e < 4; ++e) {
      long row = m0 + wr * 64 + mt * 16 + g * 4 + e;
      long bb = row >> 11;
      int tt = (int)row & 2047;
      float v0 = acc[mt][0][e] + bv[0];
      float v1 = acc[mt][1][e] + bv[1];
      float v2 = acc[mt][2][e] + bv[2];
      float v3 = acc[mt][3][e] + bv[3];
      if (which < 2) {
        float2 cs = tab[tt * 16 + r];
        float r0 = v0 * cs.x - v2 * cs.y, r2 = v2 * cs.x + v0 * cs.y;
        float r1 = v1 * cs.x - v3 * cs.y, r3 = v3 * cs.x + v1 * cs.y;
        if (which == 0) { r0 *= QSCALE; r1 *= QSCALE; r2 *= QSCALE; r3 *= QSCALE; }
        v0 = r0; v1 = r1; v2 = r2; v3 = r3;
      }
      u16* op = out + (long)which * 8388608 + (((bb * 16 + hh) * 2048 + tt) << 6);
      op[r] = f2b(v0);
      op[16 + r] = f2b(v1);
      op[32 + r] = f2b(v2);
      op[48 + r] = f2b(v3);
    }
  }
}

// ---------------- proj GEMM: out = A @ Bt^T + bias, global_load_lds staging.
// A = bf16 Yb [M][K], Bt = bf16 WpT [N][K], out fp32 [M][N].
__global__ __launch_bounds__(256) void gemm_proj_k(const u16* __restrict__ A,
                                                   const u16* __restrict__ Bt,
                                                   const float* __restrict__ bias,
                                                   float* __restrict__ out,
                                                   int M, int N, int K) {
  __shared__ u16 As[128 * 32];
  __shared__ u16 Bs[128 * 32];
  int tid = threadIdx.x, wid = tid >> 6, lane = tid & 63;
  int wr = wid >> 1, wc = wid & 1;
  long m0 = (long)blockIdx.x * 128, n0 = (long)blockIdx.y * 128;
  int r = lane & 15, g = lane >> 4;
  const u16* Ag = A + (m0 + wid * 32 + (lane >> 2)) * (long)K + (lane & 3) * 8;
  const u16* Bg = Bt + (n0 + wid * 32 + (lane >> 2)) * (long)K + (lane & 3) * 8;
  u16* AsW = As + wid * 1024;
  u16* BsW = Bs + wid * 1024;
  f32x4 acc[4][4] = {};
  int nk = K >> 5;
  for (int kt = 0; kt < nk; ++kt) {
    long ko = (long)kt * 32;
    GLOAD16(Ag + ko, AsW);
    GLOAD16(Ag + ko + 16 * (long)K, AsW + 512);
    GLOAD16(Bg + ko, BsW);
    GLOAD16(Bg + ko + 16 * (long)K, BsW + 512);
    __syncthreads();
    bf16x8 af[4], bfr[4];
#pragma unroll
    for (int mt = 0; mt < 4; ++mt)
      af[mt] = *(const bf16x8*)&As[(wr * 64 + mt * 16 + r) * 32 + g * 8];
#pragma unroll
    for (int nt = 0; nt < 4; ++nt)
      bfr[nt] = *(const bf16x8*)&Bs[(wc * 64 + nt * 16 + r) * 32 + g * 8];
#pragma unroll
    for (int mt = 0; mt < 4; ++mt)
#pragma unroll
      for (int nt = 0; nt < 4; ++nt)
        acc[mt][nt] = __builtin_amdgcn_mfma_f32_16x16x32_bf16(af[mt], bfr[nt], acc[mt][nt], 0, 0, 0);
    __syncthreads();
  }
#pragma unroll
  for (int nt = 0; nt < 4; ++nt) {
    long col = n0 + wc * 64 + nt * 16 + r;
    float bvv = bias[col];
#pragma unroll
    for (int mt = 0; mt < 4; ++mt)
#pragma unroll
      for (int e = 0; e < 4; ++e) {
        long row = m0 + wr * 64 + mt * 16 + g * 4 + e;
        out[row * N + col] = acc[mt][nt][e] + bvv;
      }
  }
}

// ---------------- flash attention v3: swapped-QK 32x32, in-register softmax,
// strip-paired causal load balance. Wave owns q-strips sA=4*ib+wid and sB=63-sA.
// Q,K: [bh][t][64] bf16 (Q pre-scaled), VgT: [bh][64][t]. Grid (bh=64, ib=8).
__global__ __launch_bounds__(256, 2) void attn_k(const u16* __restrict__ Qg,
                                                 const u16* __restrict__ Kg,
                                                 const u16* __restrict__ VgT,
                                                 u16* __restrict__ Y) {
  __shared__ u16 Ks[64 * 72];  // [kv 64][d 64] +8 pad
  __shared__ u16 Vt[64 * 72];  // [d 64][kv 64] +8 pad
  int ib = blockIdx.y;
  int bh = blockIdx.x;
  int b = bh >> 4, h = bh & 15;
  long base = (long)bh * (2048 * 64);
  int tid = threadIdx.x, wid = tid >> 6;
  int lane = tid & 63, l31 = lane & 31, hi = lane >> 5;
  int sA = ib * 4 + wid, sB = 63 - sA;
  int q0A = sA * 32, q0B = sB * 32;
  int endA = sA >> 1, endB = sB >> 1;
  int ktEnd = 31 - 2 * ib;  // max endB over waves in block
  bf16x8 qfA[4], qfB[4];
  {
    const u16* qa = Qg + base + (long)(q0A + l31) * 64 + hi * 8;
    const u16* qb = Qg + base + (long)(q0B + l31) * 64 + hi * 8;
#pragma unroll
    for (int s = 0; s < 4; ++s) {
      qfA[s] = *(const bf16x8*)(qa + s * 16);
      qfB[s] = *(const bf16x8*)(qb + s * 16);
    }
  }
  f32x16 accA0 = {}, accA1 = {}, accB0 = {}, accB1 = {};
  float mA = -INFINITY, lA = 0.f, mB = -INFINITY, lB = 0.f;
  for (int kt = 0; kt <= ktEnd; ++kt) {
    __syncthreads();
#pragma unroll
    for (int uu = 0; uu < 2; ++uu) {
      int u = tid + uu * 256;
      int row = u >> 3, c4 = (u & 7) * 8;
      *(uint4*)&Ks[row * 72 + c4] =
          *(const uint4*)&Kg[base + (long)(kt * 64 + row) * 64 + c4];
      *(uint4*)&Vt[row * 72 + c4] =
          *(const uint4*)&VgT[base + (long)row * 2048 + kt * 64 + c4];
    }
    __syncthreads();
    auto tileC = [&](const bf16x8 (&qf)[4], f32x16& acc0, f32x16& acc1,
                     float& mrow, float& lrow, int q0, int endS) {
      // S^T = K @ Q^T : st[ct] covers k = ct*32 + crow(reg,hi), q = l31
      f32x16 st[2];
#pragma unroll
      for (int ct = 0; ct < 2; ++ct) {
        f32x16 z = {};
#pragma unroll
        for (int s = 0; s < 4; ++s) {
          bf16x8 kf = *(const bf16x8*)&Ks[(ct * 32 + l31) * 72 + s * 16 + hi * 8];
          z = __builtin_amdgcn_mfma_f32_32x32x16_bf16(kf, qf[s], z, 0, 0, 0);
        }
        st[ct] = z;
      }
      if (kt == endS) {  // causal mask on diagonal tile
        int qg = q0 + l31;
#pragma unroll
        for (int ct = 0; ct < 2; ++ct)
#pragma unroll
          for (int reg = 0; reg < 16; ++reg) {
            int kg = kt * 64 + ct * 32 + (reg & 3) + 8 * (reg >> 2) + 4 * hi;
            if (kg > qg) st[ct][reg] = -INFINITY;
          }
      }
      // row max: in-reg tree + cross-half shfl
      float t8[8];
#pragma unroll
      for (int i = 0; i < 8; ++i)
        t8[i] = fmaxf(fmaxf(st[0][i], st[0][i + 8]), fmaxf(st[1][i], st[1][i + 8]));
#pragma unroll
      for (int i = 0; i < 4; ++i) t8[i] = fmaxf(t8[i], t8[i + 4]);
      float pm = fmaxf(fmaxf(t8[0], t8[1]), fmaxf(t8[2], t8[3]));
      pm = fmaxf(pm, __shfl_xor(pm, 32));
      // defer-max (T13)
      if (__any(pm > mrow + 8.0f)) {
        float mn = fmaxf(mrow, pm);
        float alpha = exp2f(mrow - mn);
        mrow = mn;
        lrow *= alpha;
#pragma unroll
        for (int reg = 0; reg < 16; ++reg) {
          float aB = __shfl(alpha, (reg & 3) + 8 * (reg >> 2) + 4 * hi);
          acc0[reg] *= aB;
          acc1[reg] *= aB;
        }
      }
      // p = exp2(s - mrow); row sum
      float s8[8];
#pragma unroll
      for (int i = 0; i < 8; ++i) s8[i] = 0.f;
#pragma unroll
      for (int ct = 0; ct < 2; ++ct)
#pragma unroll
        for (int reg = 0; reg < 16; ++reg) {
          float p = exp2f(st[ct][reg] - mrow);
          st[ct][reg] = p;
          s8[reg & 7] += p;
        }
#pragma unroll
      for (int i = 0; i < 4; ++i) s8[i] += s8[i + 4];
      float rs = (s8[0] + s8[1]) + (s8[2] + s8[3]);
      rs += __shfl_xor(rs, 32);
      lrow += rs;
      // PV: quad-exchange P into A-frag slots, then mfma
#pragma unroll
      for (int ct = 0; ct < 2; ++ct) {
        bf16x8 af[2];
#pragma unroll
        for (int ks = 0; ks < 2; ++ks) {
#pragma unroll
          for (int u = 0; u < 4; ++u) {
            float sendv = hi ? st[ct][8 * ks + u] : st[ct][8 * ks + 4 + u];
            float keepv = hi ? st[ct][8 * ks + 4 + u] : st[ct][8 * ks + u];
            float rcv = __shfl_xor(sendv, 32);
            af[ks][u] = (__bf16)(hi ? rcv : keepv);
            af[ks][4 + u] = (__bf16)(hi ? keepv : rcv);
          }
        }
#pragma unroll
        for (int ks = 0; ks < 2; ++ks) {
          bf16x8 vf0 = *(const bf16x8*)&Vt[l31 * 72 + ct * 32 + ks * 16 + hi * 8];
          bf16x8 vf1 = *(const bf16x8*)&Vt[(32 + l31) * 72 + ct * 32 + ks * 16 + hi * 8];
          acc0 = __builtin_amdgcn_mfma_f32_32x32x16_bf16(af[ks], vf0, acc0, 0, 0, 0);
          acc1 = __builtin_amdgcn_mfma_f32_32x32x16_bf16(af[ks], vf1, acc1, 0, 0, 0);
        }
      }
    };
    if (kt <= endA) tileC(qfA, accA0, accA1, mA, lA, q0A, endA);
    if (kt <= endB) tileC(qfB, accB0, accB1, mB, lB, q0B, endB);
  }
  auto writeO = [&](const f32x16& acc0, const f32x16& acc1, float lrow, int q0) {
    float rinv = 1.0f / lrow;
#pragma unroll
    for (int reg = 0; reg < 16; ++reg) {
      int crow = (reg & 3) + 8 * (reg >> 2) + 4 * hi;
      float rB = __shfl(rinv, crow);
      long orow = (long)(b * 2048 + q0 + crow) * 1024 + h * 64;
      Y[orow + l31] = f2b(acc0[reg] * rB);
      Y[orow + 32 + l31] = f2b(acc1[reg] * rB);
    }
  };
  writeO(accA0, accA1, lA, q0A);
  writeO(accB0, accB1, lB, q0B);
}

extern "C" void kernel_launch(void* const* d_in, const int* in_sizes, int n_in,
                              void* d_out, int out_size, void* d_ws, size_t ws_size,
                              hipStream_t stream) {
  const float* x  = (const float*)d_in[0];
  const float* Wa = (const float*)d_in[1];
  const float* ba = (const float*)d_in[2];
  const float* Wp = (const float*)d_in[3];
  const float* bp = (const float*)d_in[4];

  if (ws_size < 67108864ULL) {
    sentinel_k<<<dim3((out_size + 255) / 256), 256, 0, stream>>>((u16*)d_out, out_size);
    return;
  }

  u16* ws  = (u16*)d_ws;
  u16* Qg  = ws;                           // [0, 8388608)
  u16* Kg  = ws + 8388608;                 // [8388608, 16777216)
  u16* Vg  = ws + 16777216;                // [16777216, 25165824)
  u16* Yb  = ws + 16777216;                // over dead Vg (after V-transpose)
  u16* WaT = ws + 25165824;                // bf16, dead after QKV GEMM
  float2* tab = (float2*)(ws + 28311552);  // dead after QKV GEMM
  u16* VgT = ws + 25165824;                // over dead WaT+tab
  u16* WpT = ws;                           // over dead Qg (after attn)

  transpose_f2b_k<<<dim3(48, 16), 256, 0, stream>>>(Wa, WaT, 1024, 3072);
  rope_table_k<<<dim3(128), 256, 0, stream>>>(tab);
  gemm_qkv_k<<<dim3(64, 24), 256, 0, stream>>>(x, WaT, ba, tab, Qg, 8192, 3072, 1024);
  transpose_b_k<<<dim3(1, 32, 64), 256, 0, stream>>>(Vg, VgT, 2048, 64, 131072L, 131072L);
  attn_k<<<dim3(64, 8), 256, 0, stream>>>(Qg, Kg, VgT, Yb);
  transpose_f2b_k<<<dim3(16, 16), 256, 0, stream>>>(Wp, WpT, 1024, 1024);
  gemm_proj_k<<<dim3(64, 8), 256, 0, stream>>>(Yb, WpT, bp, (float*)d_out, 8192, 1024, 1024);
}